// Round 1
// baseline (19.660 us; speedup 1.0000x reference)
//
#include <hip/hip_runtime.h>

#define N 1024
#define C 256

// Kernel A: s[i] = dot(x[i,:], w).  One 64-lane wave per row; 4 waves/block.
__global__ void row_dot(const float* __restrict__ x, const float* __restrict__ w,
                        float* __restrict__ s) {
    int wave = threadIdx.x >> 6;          // 0..3
    int lane = threadIdx.x & 63;
    int row  = blockIdx.x * 4 + wave;
    const float4* xr = reinterpret_cast<const float4*>(x + row * C);
    const float4* wv = reinterpret_cast<const float4*>(w);
    float4 xv = xr[lane];                 // C/4 = 64 float4 per row -> lane i reads i-th
    float4 wf = wv[lane];
    float acc = xv.x * wf.x + xv.y * wf.y + xv.z * wf.z + xv.w * wf.w;
    #pragma unroll
    for (int off = 32; off > 0; off >>= 1)
        acc += __shfl_down(acc, off, 64);
    if (lane == 0) s[row] = acc;
}

// Kernel B: S1[c] = sum_j x[j,c]; S2[c] = sum_j x[j,c]*s[j]; T = sum_j s[j].
// 32 blocks, each handles 32 rows; thread c owns column c (coalesced loads).
__global__ void col_sums(const float* __restrict__ x, const float* __restrict__ s,
                         float* __restrict__ S1, float* __restrict__ S2,
                         float* __restrict__ T) {
    const int rows_per_block = N / 32;
    int c  = threadIdx.x;                 // 0..255
    int r0 = blockIdx.x * rows_per_block;
    float p1 = 0.f, p2 = 0.f;
    #pragma unroll 4
    for (int j = r0; j < r0 + rows_per_block; ++j) {
        float xv = x[j * C + c];
        float sj = s[j];
        p1 += xv;
        p2 += xv * sj;
    }
    atomicAdd(&S1[c], p1);
    atomicAdd(&S2[c], p2);
    // T partial: first wave reduces this block's s[j]
    if (threadIdx.x < 64) {
        float ts = 0.f;
        for (int j = r0 + threadIdx.x; j < r0 + rows_per_block; j += 64)
            ts += s[j];
        #pragma unroll
        for (int off = 32; off > 0; off >>= 1)
            ts += __shfl_down(ts, off, 64);
        if (threadIdx.x == 0) atomicAdd(T, ts);
    }
}

// Kernel C: out[i,c] = (s[i]+b)*S1[c] + S2[c] + x[i,c]*(N*(s[i]+b) + T)
__global__ void finalize(const float* __restrict__ x, const float* __restrict__ s,
                         const float* __restrict__ S1, const float* __restrict__ S2,
                         const float* __restrict__ T, const float* __restrict__ bptr,
                         float* __restrict__ out) {
    int i = blockIdx.x;
    int c = threadIdx.x;
    float sb = s[i] + bptr[0];
    float t  = T[0];
    float xv = x[i * C + c];
    out[i * C + c] = sb * S1[c] + S2[c] + xv * ((float)N * sb + t);
}

extern "C" void kernel_launch(void* const* d_in, const int* in_sizes, int n_in,
                              void* d_out, int out_size, void* d_ws, size_t ws_size,
                              hipStream_t stream) {
    const float* x = (const float*)d_in[0];
    const float* w = (const float*)d_in[1];
    const float* b = (const float*)d_in[2];
    float* out = (float*)d_out;

    // workspace layout (floats): s[N] | S1[C] | S2[C] | T[1]
    float* s  = (float*)d_ws;
    float* S1 = s + N;
    float* S2 = S1 + C;
    float* T  = S2 + C;

    // zero the atomic accumulators (harness does not re-poison between replays)
    hipMemsetAsync(S1, 0, (2 * C + 1) * sizeof(float), stream);

    row_dot <<<N / 4, 256, 0, stream>>>(x, w, s);
    col_sums<<<32,    256, 0, stream>>>(x, s, S1, S2, T);
    finalize<<<N,     256, 0, stream>>>(x, s, S1, S2, T, b, out);
}

// Round 2
// 13.457 us; speedup vs baseline: 1.4610x; 1.4610x over previous
//
#include <hip/hip_runtime.h>

#define N 1024
#define C 256
#define NB1 32          // phase-1 blocks; each handles N/NB1 = 32 rows
#define ROWS1 (N / NB1) // 32
#define NB2 128         // phase-2 blocks; each handles N/NB2 = 8 rows
#define ROWS2 (N / NB2) // 8

// Phase 1: per block b (32 rows starting r0=b*32):
//   s[j]     = dot(x[j,:], w)                      (wave-per-row, shuffle reduce)
//   S1p[b,c] = sum_{j in block} x[j,c]
//   S2p[b,c] = sum_{j in block} x[j,c] * s[j]
//   Tp[b]    = sum_{j in block} s[j]
__global__ void phase1(const float* __restrict__ x, const float* __restrict__ w,
                       float* __restrict__ s, float* __restrict__ S1p,
                       float* __restrict__ S2p, float* __restrict__ Tp) {
    __shared__ float s_lds[ROWS1];
    const int b    = blockIdx.x;
    const int r0   = b * ROWS1;
    const int wave = threadIdx.x >> 6;   // 0..3
    const int lane = threadIdx.x & 63;

    const float4* wv = reinterpret_cast<const float4*>(w);
    const float4  wf = wv[lane];         // lane covers channels lane*4..lane*4+3

    // 4 waves x 8 rows each
    #pragma unroll
    for (int k = 0; k < ROWS1 / 4; ++k) {
        const int lrow = wave * (ROWS1 / 4) + k;
        const int row  = r0 + lrow;
        const float4 xv = reinterpret_cast<const float4*>(x + row * C)[lane];
        float acc = xv.x * wf.x + xv.y * wf.y + xv.z * wf.z + xv.w * wf.w;
        #pragma unroll
        for (int off = 32; off > 0; off >>= 1)
            acc += __shfl_down(acc, off, 64);
        if (lane == 0) { s_lds[lrow] = acc; s[row] = acc; }
    }
    __syncthreads();

    const int c = threadIdx.x;
    float p1 = 0.f, p2 = 0.f;
    #pragma unroll 4
    for (int j = 0; j < ROWS1; ++j) {
        const float xv = x[(r0 + j) * C + c];   // coalesced; L1/L2-hot (just read above)
        const float sj = s_lds[j];
        p1 += xv;
        p2 += xv * sj;
    }
    S1p[b * C + c] = p1;
    S2p[b * C + c] = p2;

    if (threadIdx.x == 0) {
        float t = 0.f;
        #pragma unroll
        for (int j = 0; j < ROWS1; ++j) t += s_lds[j];
        Tp[b] = t;
    }
}

// Phase 2: thread c reduces S1/S2/T over the 32 block-partials (L2-resident),
// then finalizes 8 rows:
//   out[i,c] = (s[i]+b)*S1[c] + S2[c] + x[i,c]*(N*(s[i]+b) + T)
__global__ void phase2(const float* __restrict__ x, const float* __restrict__ s,
                       const float* __restrict__ S1p, const float* __restrict__ S2p,
                       const float* __restrict__ Tp, const float* __restrict__ bptr,
                       float* __restrict__ out) {
    const int c = threadIdx.x;
    float S1 = 0.f, S2 = 0.f;
    #pragma unroll
    for (int p = 0; p < NB1; ++p) {
        S1 += S1p[p * C + c];
        S2 += S2p[p * C + c];
    }
    float T = 0.f;
    #pragma unroll
    for (int p = 0; p < NB1; ++p) T += Tp[p];   // wave-uniform broadcast loads

    const float bb = bptr[0];
    const int  r0 = blockIdx.x * ROWS2;
    #pragma unroll
    for (int k = 0; k < ROWS2; ++k) {
        const int   i  = r0 + k;
        const float sb = s[i] + bb;
        const float xv = x[i * C + c];
        out[i * C + c] = sb * S1 + S2 + xv * ((float)N * sb + T);
    }
}

extern "C" void kernel_launch(void* const* d_in, const int* in_sizes, int n_in,
                              void* d_out, int out_size, void* d_ws, size_t ws_size,
                              hipStream_t stream) {
    const float* x = (const float*)d_in[0];
    const float* w = (const float*)d_in[1];
    const float* b = (const float*)d_in[2];
    float* out = (float*)d_out;

    // workspace (floats): s[N] | S1p[NB1*C] | S2p[NB1*C] | Tp[NB1]
    float* s   = (float*)d_ws;
    float* S1p = s + N;
    float* S2p = S1p + NB1 * C;
    float* Tp  = S2p + NB1 * C;

    phase1<<<NB1, 256, 0, stream>>>(x, w, s, S1p, S2p, Tp);
    phase2<<<NB2, 256, 0, stream>>>(x, s, S1p, S2p, Tp, b, out);
}